// Round 10
// baseline (320.517 us; speedup 1.0000x reference)
//
#include <hip/hip_runtime.h>
#include <math.h>

#define HH 64
#define WW 64
#define NB 4
#define NV ((HH-1)*WW)      // 4032 vertical candidates
#define NHZ (HH*(WW-1))     // 4032 horizontal candidates
#define NP (NV+NHZ)         // 8064 candidates per image
#define EPSF 1e-3f
#define BANDF 3.0f
#define BIGF 1e10f
#define NCELL 256           // 16x16 cells of size 4; radius 3 < 4 => 3x3 ring exact
#define GPC 16              // lanes per candidate group
#define CPB (256/GPC)       // 16 candidates per block
#define NBLK (NP/CPB)       // 504 blocks per batch (8064 = 504*16 exact)
#define GRID_NN (NB*NBLK)   // 2016

// ---- ws layout ----
// float4 binEnt[NB][NP]  : (r, c, j-as-int-bits, g2)  516096 B
// int    offs[NB][NCELL+1]
// float  acc[12] : S[4], l1n[4], l1[4]
// int    ctr

__device__ __forceinline__ bool cand_point(const float* __restrict__ s, int p,
                                           float& pr, float& pc) {
  float v1, v2; int i, j; bool vert = (p < NV);
  if (vert) {
    i = p >> 6; j = p & 63;
    v1 = s[i*WW + j]; v2 = s[(i+1)*WW + j];
  } else {
    int q = p - NV; i = q / (WW-1); j = q - i*(WW-1);
    v1 = s[i*WW + j]; v2 = s[i*WW + j + 1];
  }
  float a1 = fabsf(v1), a2 = fabsf(v2);
  // sign(v1)*sign(v2)<0 == v1*v2<0 when neither |v|<=EPS (no underflow then)
  bool valid = (v1*v2 < 0.0f) || (a1 <= EPSF) || (a2 <= EPSF);
  float a = a1 / fmaxf(a1 + a2, 1e-8f);
  a = fminf(fmaxf(a, 0.0f), 1.0f);
  pr = vert ? ((float)i + a) : (float)i;
  pc = vert ? (float)j       : ((float)j + a);
  return valid;
}

__device__ __forceinline__ void normal_at(const float* __restrict__ s, int r, int c,
                                          float& nr, float& nc) {
  float grm = (r == 0)    ? (s[WW + c] - s[c])
            : (r == HH-1) ? (s[(HH-1)*WW + c] - s[(HH-2)*WW + c])
                          : 0.5f * (s[(r+1)*WW + c] - s[(r-1)*WW + c]);
  float gcm = (c == 0)    ? (s[r*WW + 1] - s[r*WW])
            : (c == WW-1) ? (s[r*WW + WW-1] - s[r*WW + WW-2])
                          : 0.5f * (s[r*WW + c + 1] - s[r*WW + c - 1]);
  nr = grm; nc = gcm;
}

// K1: 4 blocks, one per batch. Compact-j scan of gt candidates, CSR-bin them
// into 16x16 cells (entries carry r,c,j,g2), write offs; also per-batch L1
// sum and acc/ctr zeroing. (unchanged from round 9 — passed absmax 0)
__global__ __launch_bounds__(256) void k_prep(const float* __restrict__ pred,
                                              const float* __restrict__ gt,
                                              float4* __restrict__ binEnt,
                                              int* __restrict__ offs_g,
                                              float* __restrict__ acc,
                                              int* __restrict__ ctr) {
  int b = blockIdx.x;
  const float* g = gt + b*HH*WW;

  __shared__ float2 cval[NP];                  // 64512 B
  __shared__ unsigned long long cmask[4*32];
  __shared__ int wcnt[4], wbase[4];
  __shared__ int cellCnt[NCELL];               // counts, then fill cursors
  __shared__ int cellOff[NCELL+1];
  __shared__ float ws4[4];

  int tid = threadIdx.x, lane = tid & 63, wid = tid >> 6;
  for (int i = tid; i < NCELL; i += 256) cellCnt[i] = 0;
  __syncthreads();

  const int SPAN = NP / 4;                     // 2016
  int start = wid * SPAN, end = start + SPAN;

  // pass 1: validity, coords, per-wave counts, per-cell counts
  int cnt = 0;
  for (int t = 0; t < 32; ++t) {
    int p = start + t*64 + lane;
    bool v = false; float r = 0.f, c = 0.f;
    if (p < end) v = cand_point(g, p, r, c);
    unsigned long long m = __ballot(v ? 1 : 0);
    if (v) {
      cval[p] = make_float2(r, c);
      int cell = (((int)r) >> 2) * 16 + (((int)c) >> 2);
      atomicAdd(&cellCnt[cell], 1);
    }
    if (lane == 0) cmask[wid*32 + t] = m;
    cnt += __popcll(m);
  }
  if (lane == 0) wcnt[wid] = cnt;
  __syncthreads();
  if (tid == 0) {
    int run = 0;
    for (int w = 0; w < 4; ++w) { wbase[w] = run; run += wcnt[w]; }
    int s2 = 0;
    for (int i = 0; i < NCELL; ++i) { cellOff[i] = s2; s2 += cellCnt[i]; }
    cellOff[NCELL] = s2;
    acc[b] = 0.f; acc[4 + b] = 0.f;
    if (b == 0) *ctr = 0;
  }
  __syncthreads();
  for (int i = tid; i < NCELL; i += 256) cellCnt[i] = cellOff[i];   // fill cursors
  for (int i = tid; i < NCELL + 1; i += 256) offs_g[b*(NCELL+1) + i] = cellOff[i];
  __syncthreads();

  // pass 2: scatter (r, c, j, g2) into CSR bins (order within cell arbitrary;
  // NN uses lexicographic (d2,j) so first-index tie-break is preserved)
  float4* Eb = binEnt + (size_t)b * NP;
  int off = wbase[wid];
  for (int t = 0; t < 32; ++t) {
    unsigned long long m = cmask[wid*32 + t];
    int p = start + t*64 + lane;
    if ((m >> lane) & 1ull) {
      int j = off + __popcll(m & ((1ull << lane) - 1ull));   // compacted j, monotone in p
      float2 rc = cval[p];
      int cell = (((int)rc.x) >> 2) * 16 + (((int)rc.y) >> 2);
      int slot = atomicAdd(&cellCnt[cell], 1);
      float g2 = fmaf(rc.y, rc.y, rc.x * rc.x);              // same rounding as NN loop
      Eb[slot] = make_float4(rc.x, rc.y, __int_as_float(j), g2);
    }
    off += __popcll(m);
  }

  // L1 partial for batch b
  const float* pr = pred + b*HH*WW;
  float loc = 0.f;
  for (int p = tid; p < HH*WW; p += 256) loc += fabsf(pr[p] - g[p]);
  for (int o = 32; o; o >>= 1) loc += __shfl_down(loc, o);
  if (lane == 0) ws4[wid] = loc;
  __syncthreads();
  if (tid == 0) acc[8 + b] = ws4[0] + ws4[1] + ws4[2] + ws4[3];
}

// K2: one 16-lane GROUP per P candidate (2016 blocks -> ~8 waves/SIMD TLP).
// Ring scan lane-strided 16 ways: ~9 loads/lane instead of 142 serial.
// Row-clamp duplication is harmless (lexicographic min is idempotent).
// Lexicographic (d2,j) 16-lane butterfly = reference first-index argmin.
// Fused finalize via completion counter.
__global__ __launch_bounds__(256) void k_nn(const float* __restrict__ pred,
                                            const float4* __restrict__ binEnt,
                                            const int* __restrict__ offs_g,
                                            float* __restrict__ acc,
                                            int* __restrict__ ctr,
                                            float* __restrict__ out) {
  __shared__ int lastFlag;

  int bb = blockIdx.x;
  int b = bb / NBLK, blk = bb - b * NBLK;
  int tid = threadIdx.x;
  int s = tid & 15, grp = tid >> 4;
  int p = blk * CPB + grp;                   // candidate index, < NP always
  const float* sp = pred + b*HH*WW;
  const int* offs = offs_g + b * (NCELL + 1);

  float contribS = 0.f, contribN = 0.f;
  float prr = 0.f, pcc = 0.f;
  bool vP = cand_point(sp, p, prr, pcc);     // all 16 lanes redundantly

  if (vP) {
    float p2 = prr*prr + pcc*pcc;
    const float4* E = binEnt + (size_t)b * NP;
    int cr = ((int)prr) >> 2, cc = ((int)pcc) >> 2;
    int rr0 = max(cr - 1, 0), rr1 = cr, rr2 = min(cr + 1, 15);
    int clo = max(cc - 1, 0), chi = min(cc + 1, 15);
    // 6 independent group-uniform span loads (clamped rows may duplicate)
    int beg0 = offs[rr0*16 + clo], end0 = offs[rr0*16 + chi + 1];
    int beg1 = offs[rr1*16 + clo], end1 = offs[rr1*16 + chi + 1];
    int beg2 = offs[rr2*16 + clo], end2 = offs[rr2*16 + chi + 1];

    float bd = BIGF, br = 0.f, bc = 0.f; int bj = 0x7fffffff;
    #pragma unroll
    for (int span = 0; span < 3; ++span) {
      int beg = (span == 0) ? beg0 : (span == 1) ? beg1 : beg2;
      int end = (span == 0) ? end0 : (span == 1) ? end1 : end2;
      for (int e = beg + s; e < end; e += GPC) {
        float4 ge = E[e];
        float t  = fmaf(ge.y, pcc, ge.x * prr);
        float dd = fmaf(-2.f, t, p2 + ge.w);
        int   j  = __float_as_int(ge.z);
        if (dd < bd || (dd == bd && j < bj)) { bd = dd; bj = j; br = ge.x; bc = ge.y; }
      }
    }
    // 16-lane butterfly, lexicographic (d2, j)
    for (int moff = 1; moff <= 8; moff <<= 1) {
      float od = __shfl_xor(bd, moff);
      int   oj = __shfl_xor(bj, moff);
      float orr = __shfl_xor(br, moff);
      float occ = __shfl_xor(bc, moff);
      if (od < bd || (od == bd && oj < bj)) { bd = od; bj = oj; br = orr; bc = occ; }
    }

    if (s == 0) {
      // ring-min == global min whenever <= BAND (radius 3 < cell 4);
      // ring-min > BAND => reference-masked => contribute 0 (covers empty ring)
      float minP = sqrtf(fmaxf(bd, 0.f));
      if (minP <= BANDF) {
        int r0 = min(max((int)floorf(prr), 0), HH-1);
        int c0 = min(max((int)floorf(pcc), 0), WW-1);
        int r1 = min(r0 + 1, HH-1), c1 = min(c0 + 1, WW-1);
        float dr = prr - (float)r0, dc = pcc - (float)c0;
        float w00 = (1.f-dr)*(1.f-dc), w01 = (1.f-dr)*dc;
        float w10 = dr*(1.f-dc),       w11 = dr*dc;
        float nar, nac, nbr, nbc, ncr, ncc, ndr, ndc;
        normal_at(sp, r0, c0, nar, nac);
        normal_at(sp, r0, c1, nbr, nbc);
        normal_at(sp, r1, c0, ncr, ncc);
        normal_at(sp, r1, c1, ndr, ndc);
        float nr  = w00*nar + w01*nbr + w10*ncr + w11*ndr;
        float nc2 = w00*nac + w01*nbc + w10*ncc + w11*ndc;
        float bilin = w00*sp[r0*WW+c0] + w01*sp[r0*WW+c1]
                    + w10*sp[r1*WW+c0] + w11*sp[r1*WW+c1];
        float dlr = br - prr, dlc = bc - pcc;   // G[idx] - P
        contribN = fabsf(nr) + fabsf(nc2);
        contribS = (dlr*nr + dlc*nc2) * bilin;
      }
    }
  }

  // wave sum (nonzero only at s==0 lanes), one atomic per wave
  for (int o = 1; o < 64; o <<= 1) {
    contribS += __shfl_xor(contribS, o);
    contribN += __shfl_xor(contribN, o);
  }
  if ((tid & 63) == 0 && (contribS != 0.f || contribN != 0.f)) {
    atomicAdd(&acc[b],     contribS);
    atomicAdd(&acc[4 + b], contribN);
  }

  // fused finalize: last of the GRID_NN blocks computes the scalar
  __threadfence();
  if (tid == 0) {
    int old = atomicAdd(ctr, 1);
    lastFlag = (old == GRID_NN - 1) ? 1 : 0;
  }
  __syncthreads();
  if (lastFlag && tid == 0) {
    float ps = 0.f, l1 = 0.f;
    for (int bi = 0; bi < NB; ++bi) {
      float S = atomicAdd(&acc[bi], 0.f);       // coherent read
      float N = atomicAdd(&acc[4 + bi], 0.f);
      ps += -(S / (N + 1e-8f));                 // pseudo_b (SCALE=1, NORM_N)
      l1 += acc[8 + bi];                        // written by k_prep
    }
    out[0] = ps * (1.0f / NB) + l1 * (1.0f / (NB * HH * WW));
  }
}

extern "C" void kernel_launch(void* const* d_in, const int* in_sizes, int n_in,
                              void* d_out, int out_size, void* d_ws, size_t ws_size,
                              hipStream_t stream) {
  const float* pred = (const float*)d_in[0];
  const float* gt   = (const float*)d_in[1];
  float* out = (float*)d_out;

  float4* binEnt = (float4*)d_ws;                                  // NB*NP*16
  int*    offs_g = (int*)((char*)d_ws + (size_t)NB * NP * 16);     // NB*(NCELL+1)
  float*  acc    = (float*)(offs_g + NB * (NCELL + 1));            // 12 floats
  int*    ctr    = (int*)(acc + 12);

  k_prep<<<NB, 256, 0, stream>>>(pred, gt, binEnt, offs_g, acc, ctr);
  k_nn<<<GRID_NN, 256, 0, stream>>>(pred, binEnt, offs_g, acc, ctr, out);
}

// Round 17
// 139.329 us; speedup vs baseline: 2.3004x; 2.3004x over previous
//
#include <hip/hip_runtime.h>
#include <math.h>

#define HH 64
#define WW 64
#define NB 4
#define NV ((HH-1)*WW)      // 4032 vertical candidates
#define NHZ (HH*(WW-1))     // 4032 horizontal candidates
#define NP (NV+NHZ)         // 8064 candidates per image
#define EPSF 1e-3f
#define BANDF 3.0f
#define BIGF 1e10f
#define NCELL 256           // 16x16 cells of size 4; radius 3 < 4 => 3x3 ring exact
#define GPC 16              // lanes per candidate group
#define CPB (256/GPC)       // 16 candidates per block
#define NBLK (NP/CPB)       // 504 blocks per batch (8064 = 504*16 exact)
#define GRID_NN (NB*NBLK)   // 2016

// ---- ws layout ----
// float4 binEnt[NB][NP]  : (r, c, j-as-int-bits, g2)  516096 B
// int    offs[NB][NCELL+1]
// float  acc[12] : S[4], l1n[4], l1[4]

__device__ __forceinline__ bool cand_point(const float* __restrict__ s, int p,
                                           float& pr, float& pc) {
  float v1, v2; int i, j; bool vert = (p < NV);
  if (vert) {
    i = p >> 6; j = p & 63;
    v1 = s[i*WW + j]; v2 = s[(i+1)*WW + j];
  } else {
    int q = p - NV; i = q / (WW-1); j = q - i*(WW-1);
    v1 = s[i*WW + j]; v2 = s[i*WW + j + 1];
  }
  float a1 = fabsf(v1), a2 = fabsf(v2);
  // sign(v1)*sign(v2)<0 == v1*v2<0 when neither |v|<=EPS (no underflow then)
  bool valid = (v1*v2 < 0.0f) || (a1 <= EPSF) || (a2 <= EPSF);
  float a = a1 / fmaxf(a1 + a2, 1e-8f);
  a = fminf(fmaxf(a, 0.0f), 1.0f);
  pr = vert ? ((float)i + a) : (float)i;
  pc = vert ? (float)j       : ((float)j + a);
  return valid;
}

__device__ __forceinline__ void normal_at(const float* __restrict__ s, int r, int c,
                                          float& nr, float& nc) {
  float grm = (r == 0)    ? (s[WW + c] - s[c])
            : (r == HH-1) ? (s[(HH-1)*WW + c] - s[(HH-2)*WW + c])
                          : 0.5f * (s[(r+1)*WW + c] - s[(r-1)*WW + c]);
  float gcm = (c == 0)    ? (s[r*WW + 1] - s[r*WW])
            : (c == WW-1) ? (s[r*WW + WW-1] - s[r*WW + WW-2])
                          : 0.5f * (s[r*WW + c + 1] - s[r*WW + c - 1]);
  nr = grm; nc = gcm;
}

// K1: 4 blocks, one per batch. Compact-j scan of gt candidates, CSR-bin them
// into 16x16 cells (entries carry r,c,j,g2), write offs; also per-batch L1
// sum and acc zeroing.
__global__ __launch_bounds__(256) void k_prep(const float* __restrict__ pred,
                                              const float* __restrict__ gt,
                                              float4* __restrict__ binEnt,
                                              int* __restrict__ offs_g,
                                              float* __restrict__ acc) {
  int b = blockIdx.x;
  const float* g = gt + b*HH*WW;

  __shared__ float2 cval[NP];                  // 64512 B
  __shared__ unsigned long long cmask[4*32];
  __shared__ int wcnt[4], wbase[4];
  __shared__ int cellCnt[NCELL];               // counts, then fill cursors
  __shared__ int cellOff[NCELL+1];
  __shared__ float ws4[4];

  int tid = threadIdx.x, lane = tid & 63, wid = tid >> 6;
  for (int i = tid; i < NCELL; i += 256) cellCnt[i] = 0;
  __syncthreads();

  const int SPAN = NP / 4;                     // 2016
  int start = wid * SPAN, end = start + SPAN;

  // pass 1: validity, coords, per-wave counts, per-cell counts
  int cnt = 0;
  for (int t = 0; t < 32; ++t) {
    int p = start + t*64 + lane;
    bool v = false; float r = 0.f, c = 0.f;
    if (p < end) v = cand_point(g, p, r, c);
    unsigned long long m = __ballot(v ? 1 : 0);
    if (v) {
      cval[p] = make_float2(r, c);
      int cell = (((int)r) >> 2) * 16 + (((int)c) >> 2);
      atomicAdd(&cellCnt[cell], 1);
    }
    if (lane == 0) cmask[wid*32 + t] = m;
    cnt += __popcll(m);
  }
  if (lane == 0) wcnt[wid] = cnt;
  __syncthreads();
  if (tid == 0) {
    int run = 0;
    for (int w = 0; w < 4; ++w) { wbase[w] = run; run += wcnt[w]; }
    int s2 = 0;
    for (int i = 0; i < NCELL; ++i) { cellOff[i] = s2; s2 += cellCnt[i]; }
    cellOff[NCELL] = s2;
    acc[b] = 0.f; acc[4 + b] = 0.f;
  }
  __syncthreads();
  for (int i = tid; i < NCELL; i += 256) cellCnt[i] = cellOff[i];   // fill cursors
  for (int i = tid; i < NCELL + 1; i += 256) offs_g[b*(NCELL+1) + i] = cellOff[i];
  __syncthreads();

  // pass 2: scatter (r, c, j, g2) into CSR bins (order within cell arbitrary;
  // NN uses lexicographic (d2,j) so first-index tie-break is preserved)
  float4* Eb = binEnt + (size_t)b * NP;
  int off = wbase[wid];
  for (int t = 0; t < 32; ++t) {
    unsigned long long m = cmask[wid*32 + t];
    int p = start + t*64 + lane;
    if ((m >> lane) & 1ull) {
      int j = off + __popcll(m & ((1ull << lane) - 1ull));   // compacted j, monotone in p
      float2 rc = cval[p];
      int cell = (((int)rc.x) >> 2) * 16 + (((int)rc.y) >> 2);
      int slot = atomicAdd(&cellCnt[cell], 1);
      float g2 = fmaf(rc.y, rc.y, rc.x * rc.x);              // same rounding as NN loop
      Eb[slot] = make_float4(rc.x, rc.y, __int_as_float(j), g2);
    }
    off += __popcll(m);
  }

  // L1 partial for batch b
  const float* pr = pred + b*HH*WW;
  float loc = 0.f;
  for (int p = tid; p < HH*WW; p += 256) loc += fabsf(pr[p] - g[p]);
  for (int o = 32; o; o >>= 1) loc += __shfl_down(loc, o);
  if (lane == 0) ws4[wid] = loc;
  __syncthreads();
  if (tid == 0) acc[8 + b] = ws4[0] + ws4[1] + ws4[2] + ws4[3];
}

// K2: one 16-lane GROUP per P candidate (2016 blocks -> high TLP). Ring scan
// lane-strided 16 ways. NO device fences / completion counters (that was the
// 100-130 ns/block serializer in rounds 2-10). Per-block LDS reduce -> 2
// atomics per block.
__global__ __launch_bounds__(256) void k_nn(const float* __restrict__ pred,
                                            const float4* __restrict__ binEnt,
                                            const int* __restrict__ offs_g,
                                            float* __restrict__ acc) {
  __shared__ float redS[4], redN[4];

  int bb = blockIdx.x;
  int b = bb / NBLK, blk = bb - b * NBLK;
  int tid = threadIdx.x;
  int s = tid & 15, grp = tid >> 4;
  int p = blk * CPB + grp;                   // candidate index, < NP always
  const float* sp = pred + b*HH*WW;
  const int* offs = offs_g + b * (NCELL + 1);

  float contribS = 0.f, contribN = 0.f;
  float prr = 0.f, pcc = 0.f;
  bool vP = cand_point(sp, p, prr, pcc);     // all 16 lanes redundantly

  if (vP) {
    float p2 = prr*prr + pcc*pcc;
    const float4* E = binEnt + (size_t)b * NP;
    int cr = ((int)prr) >> 2, cc = ((int)pcc) >> 2;
    int rr0 = max(cr - 1, 0), rr1 = cr, rr2 = min(cr + 1, 15);
    int clo = max(cc - 1, 0), chi = min(cc + 1, 15);
    // 6 independent group-uniform span loads (clamped rows may duplicate)
    int beg0 = offs[rr0*16 + clo], end0 = offs[rr0*16 + chi + 1];
    int beg1 = offs[rr1*16 + clo], end1 = offs[rr1*16 + chi + 1];
    int beg2 = offs[rr2*16 + clo], end2 = offs[rr2*16 + chi + 1];

    float bd = BIGF, br = 0.f, bc = 0.f; int bj = 0x7fffffff;
    #pragma unroll
    for (int span = 0; span < 3; ++span) {
      int beg = (span == 0) ? beg0 : (span == 1) ? beg1 : beg2;
      int end = (span == 0) ? end0 : (span == 1) ? end1 : end2;
      for (int e = beg + s; e < end; e += GPC) {
        float4 ge = E[e];
        float t  = fmaf(ge.y, pcc, ge.x * prr);
        float dd = fmaf(-2.f, t, p2 + ge.w);
        int   j  = __float_as_int(ge.z);
        if (dd < bd || (dd == bd && j < bj)) { bd = dd; bj = j; br = ge.x; bc = ge.y; }
      }
    }
    // 16-lane butterfly, lexicographic (d2, j) = first-index argmin
    for (int moff = 1; moff <= 8; moff <<= 1) {
      float od = __shfl_xor(bd, moff);
      int   oj = __shfl_xor(bj, moff);
      float orr = __shfl_xor(br, moff);
      float occ = __shfl_xor(bc, moff);
      if (od < bd || (od == bd && oj < bj)) { bd = od; bj = oj; br = orr; bc = occ; }
    }

    if (s == 0) {
      // ring-min == global min whenever <= BAND (radius 3 < cell 4);
      // ring-min > BAND => reference-masked => contribute 0 (covers empty ring)
      float minP = sqrtf(fmaxf(bd, 0.f));
      if (minP <= BANDF) {
        int r0 = min(max((int)floorf(prr), 0), HH-1);
        int c0 = min(max((int)floorf(pcc), 0), WW-1);
        int r1 = min(r0 + 1, HH-1), c1 = min(c0 + 1, WW-1);
        float dr = prr - (float)r0, dc = pcc - (float)c0;
        float w00 = (1.f-dr)*(1.f-dc), w01 = (1.f-dr)*dc;
        float w10 = dr*(1.f-dc),       w11 = dr*dc;
        float nar, nac, nbr, nbc, ncr, ncc, ndr, ndc;
        normal_at(sp, r0, c0, nar, nac);
        normal_at(sp, r0, c1, nbr, nbc);
        normal_at(sp, r1, c0, ncr, ncc);
        normal_at(sp, r1, c1, ndr, ndc);
        float nr  = w00*nar + w01*nbr + w10*ncr + w11*ndr;
        float nc2 = w00*nac + w01*nbc + w10*ncc + w11*ndc;
        float bilin = w00*sp[r0*WW+c0] + w01*sp[r0*WW+c1]
                    + w10*sp[r1*WW+c0] + w11*sp[r1*WW+c1];
        float dlr = br - prr, dlc = bc - pcc;   // G[idx] - P
        contribN = fabsf(nr) + fabsf(nc2);
        contribS = (dlr*nr + dlc*nc2) * bilin;
      }
    }
  }

  // wave sum, then block LDS reduce -> 2 atomics per block
  for (int o = 1; o < 64; o <<= 1) {
    contribS += __shfl_xor(contribS, o);
    contribN += __shfl_xor(contribN, o);
  }
  int wid = tid >> 6;
  if ((tid & 63) == 0) { redS[wid] = contribS; redN[wid] = contribN; }
  __syncthreads();
  if (tid == 0) {
    float Sb = redS[0] + redS[1] + redS[2] + redS[3];
    float Nb = redN[0] + redN[1] + redN[2] + redN[3];
    if (Sb != 0.f || Nb != 0.f) {
      atomicAdd(&acc[b],     Sb);
      atomicAdd(&acc[4 + b], Nb);
    }
  }
}

// K3: finalize scalar (kernel boundary = full visibility of k_nn's atomics).
__global__ void k_fin(const float* __restrict__ acc, float* __restrict__ out) {
  if (threadIdx.x == 0 && blockIdx.x == 0) {
    float ps = 0.f, l1 = 0.f;
    for (int bi = 0; bi < NB; ++bi) {
      ps += -(acc[bi] / (acc[4 + bi] + 1e-8f));   // pseudo_b (SCALE=1, NORM_N)
      l1 += acc[8 + bi];
    }
    out[0] = ps * (1.0f / NB) + l1 * (1.0f / (NB * HH * WW));
  }
}

extern "C" void kernel_launch(void* const* d_in, const int* in_sizes, int n_in,
                              void* d_out, int out_size, void* d_ws, size_t ws_size,
                              hipStream_t stream) {
  const float* pred = (const float*)d_in[0];
  const float* gt   = (const float*)d_in[1];
  float* out = (float*)d_out;

  float4* binEnt = (float4*)d_ws;                                  // NB*NP*16
  int*    offs_g = (int*)((char*)d_ws + (size_t)NB * NP * 16);     // NB*(NCELL+1)
  float*  acc    = (float*)(offs_g + NB * (NCELL + 1));            // 12 floats

  k_prep<<<NB, 256, 0, stream>>>(pred, gt, binEnt, offs_g, acc);
  k_nn<<<GRID_NN, 256, 0, stream>>>(pred, binEnt, offs_g, acc);
  k_fin<<<1, 64, 0, stream>>>(acc, out);
}

// Round 18
// 93.522 us; speedup vs baseline: 3.4272x; 1.4898x over previous
//
#include <hip/hip_runtime.h>
#include <math.h>

#define HH 64
#define WW 64
#define NB 4
#define NV ((HH-1)*WW)      // 4032 vertical candidates
#define NHZ (HH*(WW-1))     // 4032 horizontal candidates
#define NP (NV+NHZ)         // 8064 candidates per image
#define EPSF 1e-3f
#define BANDF 3.0f
#define BIGF 1e10f
#define NCELL 256           // 16x16 cells of size 4; radius 3 < 4 => 3x3 ring exact
#define GPC 16              // lanes per candidate group
#define CPB (256/GPC)       // 16 candidates per block
#define NBLK (NP/CPB)       // 504 blocks per batch (8064 = 504*16 exact)
#define GRID_NN (NB*NBLK)   // 2016

// ---- ws layout ----
// float4 binEnt[NB][NP]   : (r, c, j-as-int-bits, g2)  516096 B
// int    offs[NB][NCELL+1]
// float  accL1[NB]
// float2 partial[GRID_NN] : per-block (S, N) — NO atomics anywhere in k_nn

__device__ __forceinline__ bool cand_point(const float* __restrict__ s, int p,
                                           float& pr, float& pc) {
  float v1, v2; int i, j; bool vert = (p < NV);
  if (vert) {
    i = p >> 6; j = p & 63;
    v1 = s[i*WW + j]; v2 = s[(i+1)*WW + j];
  } else {
    int q = p - NV; i = q / (WW-1); j = q - i*(WW-1);
    v1 = s[i*WW + j]; v2 = s[i*WW + j + 1];
  }
  float a1 = fabsf(v1), a2 = fabsf(v2);
  // sign(v1)*sign(v2)<0 == v1*v2<0 when neither |v|<=EPS (no underflow then)
  bool valid = (v1*v2 < 0.0f) || (a1 <= EPSF) || (a2 <= EPSF);
  float a = a1 / fmaxf(a1 + a2, 1e-8f);
  a = fminf(fmaxf(a, 0.0f), 1.0f);
  pr = vert ? ((float)i + a) : (float)i;
  pc = vert ? (float)j       : ((float)j + a);
  return valid;
}

__device__ __forceinline__ void normal_at(const float* __restrict__ s, int r, int c,
                                          float& nr, float& nc) {
  float grm = (r == 0)    ? (s[WW + c] - s[c])
            : (r == HH-1) ? (s[(HH-1)*WW + c] - s[(HH-2)*WW + c])
                          : 0.5f * (s[(r+1)*WW + c] - s[(r-1)*WW + c]);
  float gcm = (c == 0)    ? (s[r*WW + 1] - s[r*WW])
            : (c == WW-1) ? (s[r*WW + WW-1] - s[r*WW + WW-2])
                          : 0.5f * (s[r*WW + c + 1] - s[r*WW + c - 1]);
  nr = grm; nc = gcm;
}

// K1: 4 blocks, one per batch. Compact-j scan of gt candidates, CSR-bin them
// into 16x16 cells (entries carry r,c,j,g2), write offs; also per-batch L1 sum.
__global__ __launch_bounds__(256) void k_prep(const float* __restrict__ pred,
                                              const float* __restrict__ gt,
                                              float4* __restrict__ binEnt,
                                              int* __restrict__ offs_g,
                                              float* __restrict__ accL1) {
  int b = blockIdx.x;
  const float* g = gt + b*HH*WW;

  __shared__ float2 cval[NP];                  // 64512 B
  __shared__ unsigned long long cmask[4*32];
  __shared__ int wcnt[4], wbase[4];
  __shared__ int cellCnt[NCELL];               // counts, then fill cursors
  __shared__ int cellOff[NCELL+1];
  __shared__ float ws4[4];

  int tid = threadIdx.x, lane = tid & 63, wid = tid >> 6;
  for (int i = tid; i < NCELL; i += 256) cellCnt[i] = 0;
  __syncthreads();

  const int SPAN = NP / 4;                     // 2016
  int start = wid * SPAN, end = start + SPAN;

  // pass 1: validity, coords, per-wave counts, per-cell counts
  int cnt = 0;
  for (int t = 0; t < 32; ++t) {
    int p = start + t*64 + lane;
    bool v = false; float r = 0.f, c = 0.f;
    if (p < end) v = cand_point(g, p, r, c);
    unsigned long long m = __ballot(v ? 1 : 0);
    if (v) {
      cval[p] = make_float2(r, c);
      int cell = (((int)r) >> 2) * 16 + (((int)c) >> 2);
      atomicAdd(&cellCnt[cell], 1);            // LDS atomic (cheap)
    }
    if (lane == 0) cmask[wid*32 + t] = m;
    cnt += __popcll(m);
  }
  if (lane == 0) wcnt[wid] = cnt;
  __syncthreads();
  if (tid == 0) {
    int run = 0;
    for (int w = 0; w < 4; ++w) { wbase[w] = run; run += wcnt[w]; }
    int s2 = 0;
    for (int i = 0; i < NCELL; ++i) { cellOff[i] = s2; s2 += cellCnt[i]; }
    cellOff[NCELL] = s2;
  }
  __syncthreads();
  for (int i = tid; i < NCELL; i += 256) cellCnt[i] = cellOff[i];   // fill cursors
  for (int i = tid; i < NCELL + 1; i += 256) offs_g[b*(NCELL+1) + i] = cellOff[i];
  __syncthreads();

  // pass 2: scatter (r, c, j, g2) into CSR bins (order within cell arbitrary;
  // NN uses lexicographic (d2,j) so first-index tie-break is preserved)
  float4* Eb = binEnt + (size_t)b * NP;
  int off = wbase[wid];
  for (int t = 0; t < 32; ++t) {
    unsigned long long m = cmask[wid*32 + t];
    int p = start + t*64 + lane;
    if ((m >> lane) & 1ull) {
      int j = off + __popcll(m & ((1ull << lane) - 1ull));   // compacted j, monotone in p
      float2 rc = cval[p];
      int cell = (((int)rc.x) >> 2) * 16 + (((int)rc.y) >> 2);
      int slot = atomicAdd(&cellCnt[cell], 1);
      float g2 = fmaf(rc.y, rc.y, rc.x * rc.x);              // same rounding as NN loop
      Eb[slot] = make_float4(rc.x, rc.y, __int_as_float(j), g2);
    }
    off += __popcll(m);
  }

  // L1 partial for batch b (plain store, no atomics)
  const float* pr = pred + b*HH*WW;
  float loc = 0.f;
  for (int p = tid; p < HH*WW; p += 256) loc += fabsf(pr[p] - g[p]);
  for (int o = 32; o; o >>= 1) loc += __shfl_down(loc, o);
  if (lane == 0) ws4[wid] = loc;
  __syncthreads();
  if (tid == 0) accL1[b] = ws4[0] + ws4[1] + ws4[2] + ws4[3];
}

// K2: one 16-lane GROUP per P candidate (2016 blocks -> high TLP). Ring scan
// lane-strided 16 ways. ZERO global atomics: per-block LDS reduce, then ONE
// plain float2 store to partial[bb]. (R17 evidence: 4032 same-line atomics
// cost ~14 ns each = the 58 us floor.)
__global__ __launch_bounds__(256) void k_nn(const float* __restrict__ pred,
                                            const float4* __restrict__ binEnt,
                                            const int* __restrict__ offs_g,
                                            float2* __restrict__ partial) {
  __shared__ float redS[4], redN[4];

  int bb = blockIdx.x;
  int b = bb / NBLK, blk = bb - b * NBLK;
  int tid = threadIdx.x;
  int s = tid & 15, grp = tid >> 4;
  int p = blk * CPB + grp;                   // candidate index, < NP always
  const float* sp = pred + b*HH*WW;
  const int* offs = offs_g + b * (NCELL + 1);

  float contribS = 0.f, contribN = 0.f;
  float prr = 0.f, pcc = 0.f;
  bool vP = cand_point(sp, p, prr, pcc);     // all 16 lanes redundantly

  if (vP) {
    float p2 = prr*prr + pcc*pcc;
    const float4* E = binEnt + (size_t)b * NP;
    int cr = ((int)prr) >> 2, cc = ((int)pcc) >> 2;
    int rr0 = max(cr - 1, 0), rr1 = cr, rr2 = min(cr + 1, 15);
    int clo = max(cc - 1, 0), chi = min(cc + 1, 15);
    // 6 independent group-uniform span loads (clamped rows may duplicate)
    int beg0 = offs[rr0*16 + clo], end0 = offs[rr0*16 + chi + 1];
    int beg1 = offs[rr1*16 + clo], end1 = offs[rr1*16 + chi + 1];
    int beg2 = offs[rr2*16 + clo], end2 = offs[rr2*16 + chi + 1];

    float bd = BIGF, br = 0.f, bc = 0.f; int bj = 0x7fffffff;
    #pragma unroll
    for (int span = 0; span < 3; ++span) {
      int beg = (span == 0) ? beg0 : (span == 1) ? beg1 : beg2;
      int end = (span == 0) ? end0 : (span == 1) ? end1 : end2;
      for (int e = beg + s; e < end; e += GPC) {
        float4 ge = E[e];
        float t  = fmaf(ge.y, pcc, ge.x * prr);
        float dd = fmaf(-2.f, t, p2 + ge.w);
        int   j  = __float_as_int(ge.z);
        if (dd < bd || (dd == bd && j < bj)) { bd = dd; bj = j; br = ge.x; bc = ge.y; }
      }
    }
    // 16-lane butterfly, lexicographic (d2, j) = first-index argmin
    for (int moff = 1; moff <= 8; moff <<= 1) {
      float od = __shfl_xor(bd, moff);
      int   oj = __shfl_xor(bj, moff);
      float orr = __shfl_xor(br, moff);
      float occ = __shfl_xor(bc, moff);
      if (od < bd || (od == bd && oj < bj)) { bd = od; bj = oj; br = orr; bc = occ; }
    }

    if (s == 0) {
      // ring-min == global min whenever <= BAND (radius 3 < cell 4);
      // ring-min > BAND => reference-masked => contribute 0 (covers empty ring)
      float minP = sqrtf(fmaxf(bd, 0.f));
      if (minP <= BANDF) {
        int r0 = min(max((int)floorf(prr), 0), HH-1);
        int c0 = min(max((int)floorf(pcc), 0), WW-1);
        int r1 = min(r0 + 1, HH-1), c1 = min(c0 + 1, WW-1);
        float dr = prr - (float)r0, dc = pcc - (float)c0;
        float w00 = (1.f-dr)*(1.f-dc), w01 = (1.f-dr)*dc;
        float w10 = dr*(1.f-dc),       w11 = dr*dc;
        float nar, nac, nbr, nbc, ncr, ncc, ndr, ndc;
        normal_at(sp, r0, c0, nar, nac);
        normal_at(sp, r0, c1, nbr, nbc);
        normal_at(sp, r1, c0, ncr, ncc);
        normal_at(sp, r1, c1, ndr, ndc);
        float nr  = w00*nar + w01*nbr + w10*ncr + w11*ndr;
        float nc2 = w00*nac + w01*nbc + w10*ncc + w11*ndc;
        float bilin = w00*sp[r0*WW+c0] + w01*sp[r0*WW+c1]
                    + w10*sp[r1*WW+c0] + w11*sp[r1*WW+c1];
        float dlr = br - prr, dlc = bc - pcc;   // G[idx] - P
        contribN = fabsf(nr) + fabsf(nc2);
        contribS = (dlr*nr + dlc*nc2) * bilin;
      }
    }
  }

  // wave sum, block LDS reduce, ONE plain store (no atomics, no fences)
  for (int o = 1; o < 64; o <<= 1) {
    contribS += __shfl_xor(contribS, o);
    contribN += __shfl_xor(contribN, o);
  }
  int wid = tid >> 6;
  if ((tid & 63) == 0) { redS[wid] = contribS; redN[wid] = contribN; }
  __syncthreads();
  if (tid == 0) {
    partial[bb] = make_float2(redS[0] + redS[1] + redS[2] + redS[3],
                              redN[0] + redN[1] + redN[2] + redN[3]);
  }
}

// K3: 4 waves; wave w tree-reduces batch w's 504 partials (strided loads +
// shuffle), then thread 0 combines with L1. Kernel boundary = visibility.
__global__ __launch_bounds__(256) void k_fin(const float2* __restrict__ partial,
                                             const float* __restrict__ accL1,
                                             float* __restrict__ out) {
  __shared__ float psS[4], psN[4];
  int tid = threadIdx.x, lane = tid & 63, w = tid >> 6;

  float S = 0.f, N = 0.f;
  for (int i = lane; i < NBLK; i += 64) {
    float2 pn = partial[w * NBLK + i];
    S += pn.x; N += pn.y;
  }
  for (int o = 32; o; o >>= 1) {
    S += __shfl_down(S, o);
    N += __shfl_down(N, o);
  }
  if (lane == 0) { psS[w] = S; psN[w] = N; }
  __syncthreads();
  if (tid == 0) {
    float ps = 0.f, l1 = 0.f;
    for (int bi = 0; bi < NB; ++bi) {
      ps += -(psS[bi] / (psN[bi] + 1e-8f));   // pseudo_b (SCALE=1, NORM_N)
      l1 += accL1[bi];
    }
    out[0] = ps * (1.0f / NB) + l1 * (1.0f / (NB * HH * WW));
  }
}

extern "C" void kernel_launch(void* const* d_in, const int* in_sizes, int n_in,
                              void* d_out, int out_size, void* d_ws, size_t ws_size,
                              hipStream_t stream) {
  const float* pred = (const float*)d_in[0];
  const float* gt   = (const float*)d_in[1];
  float* out = (float*)d_out;

  float4* binEnt = (float4*)d_ws;                                  // 516096 B
  int*    offs_g = (int*)((char*)d_ws + (size_t)NB * NP * 16);     // NB*(NCELL+1)
  float*  accL1  = (float*)(offs_g + NB * (NCELL + 1));            // 4 floats
  float2* partial = (float2*)(accL1 + NB);                         // 2016 float2

  k_prep<<<NB, 256, 0, stream>>>(pred, gt, binEnt, offs_g, accL1);
  k_nn<<<GRID_NN, 256, 0, stream>>>(pred, binEnt, offs_g, partial);
  k_fin<<<1, 256, 0, stream>>>(partial, accL1, out);
}